// Round 5
// baseline (653.513 us; speedup 1.0000x reference)
//
#include <hip/hip_runtime.h>
#include <hip/hip_bf16.h>
#include <math.h>

#define DIN 128
#define DOUT 64
#define NCHAIN 4   // parallel chains per node (ILP on the pointer chase)

__device__ __forceinline__ unsigned short f2bf(float f) {
    __hip_bfloat16 h = __float2bfloat16(f);   // round-to-nearest-even
    return *reinterpret_cast<unsigned short*>(&h);
}

// ---------------------------------------------------------------------------
// Kernel 1: support = bf16(X @ W)   [n x 128] @ [128 x 64] -> [n x 64] bf16
// 32 rows per block; each thread computes 2 rows sharing the same W reads
// (the kernel was LDS-read-throughput bound on W).
// ---------------------------------------------------------------------------
__global__ __launch_bounds__(256)
void gcn_gemm(const float* __restrict__ x, const float* __restrict__ w,
              unsigned short* __restrict__ sup, int n_nodes) {
    __shared__ float ws[DIN][DOUT];      // 32 KB
    __shared__ float xs[32][DIN + 4];    // 16.9 KB

    const int t = threadIdx.x;
    const int base = blockIdx.x * 32;

    for (int i = t; i < (DIN * DOUT) / 4; i += 256)
        reinterpret_cast<float4*>(&ws[0][0])[i] =
            reinterpret_cast<const float4*>(w)[i];

    for (int i = t; i < 32 * (DIN / 4); i += 256) {
        int row = i >> 5, kq = i & 31;
        if (base + row < n_nodes) {
            float4 v = reinterpret_cast<const float4*>(x)[
                (size_t)(base + row) * (DIN / 4) + kq];
            *reinterpret_cast<float4*>(&xs[row][kq * 4]) = v;
        }
    }
    __syncthreads();

    const int r = t >> 4;     // 0..15 : rows r and r+16
    const int c = t & 15;     // 0..15 : float4 column group

    float4 aA = {0.f, 0.f, 0.f, 0.f};
    float4 aB = {0.f, 0.f, 0.f, 0.f};
    #pragma unroll
    for (int k0 = 0; k0 < DIN; k0 += 4) {
        float4 xA = *reinterpret_cast<const float4*>(&xs[r][k0]);
        float4 xB = *reinterpret_cast<const float4*>(&xs[r + 16][k0]);
        float4 w0 = *reinterpret_cast<const float4*>(&ws[k0 + 0][c * 4]);
        float4 w1 = *reinterpret_cast<const float4*>(&ws[k0 + 1][c * 4]);
        float4 w2 = *reinterpret_cast<const float4*>(&ws[k0 + 2][c * 4]);
        float4 w3 = *reinterpret_cast<const float4*>(&ws[k0 + 3][c * 4]);
        aA.x += xA.x * w0.x + xA.y * w1.x + xA.z * w2.x + xA.w * w3.x;
        aA.y += xA.x * w0.y + xA.y * w1.y + xA.z * w2.y + xA.w * w3.y;
        aA.z += xA.x * w0.z + xA.y * w1.z + xA.z * w2.z + xA.w * w3.z;
        aA.w += xA.x * w0.w + xA.y * w1.w + xA.z * w2.w + xA.w * w3.w;
        aB.x += xB.x * w0.x + xB.y * w1.x + xB.z * w2.x + xB.w * w3.x;
        aB.y += xB.x * w0.y + xB.y * w1.y + xB.z * w2.y + xB.w * w3.y;
        aB.z += xB.x * w0.z + xB.y * w1.z + xB.z * w2.z + xB.w * w3.z;
        aB.w += xB.x * w0.w + xB.y * w1.w + xB.z * w2.w + xB.w * w3.w;
    }

    int row = base + r;
    if (row < n_nodes) {
        ushort4 o = { f2bf(aA.x), f2bf(aA.y), f2bf(aA.z), f2bf(aA.w) };
        reinterpret_cast<ushort4*>(sup)[(size_t)row * (DOUT / 4) + c] = o;
    }
    row += 16;
    if (row < n_nodes) {
        ushort4 o = { f2bf(aB.x), f2bf(aB.y), f2bf(aB.z), f2bf(aB.w) };
        reinterpret_cast<ushort4*>(sup)[(size_t)row * (DOUT / 4) + c] = o;
    }
}

// ---------------------------------------------------------------------------
// Kernel 2: build per-destination linked lists (NCHAIN chains per node).
// rec packs {next:i32, src:u16 | val:bf16<<16} in 8 B (n_nodes < 65536).
// ---------------------------------------------------------------------------
__global__ __launch_bounds__(256)
void k_build(const int* __restrict__ esrc, const int* __restrict__ edst,
             const float* __restrict__ evals, int* __restrict__ head,
             int2* __restrict__ rec, int n_edges) {
    int i = blockIdx.x * 256 + threadIdx.x;
    if (i >= n_edges) return;
    int d = edst[i];
    int prev = atomicExch(&head[NCHAIN * d + (i & (NCHAIN - 1))], i);
    unsigned int packed = (unsigned int)(esrc[i] & 0xFFFF) |
                          ((unsigned int)f2bf(evals[i]) << 16);
    rec[i] = make_int2(prev, (int)packed);
}

// ---------------------------------------------------------------------------
// Kernel 3: per-node gather-reduce + bias + ELU. One wave per node,
// lane = feature. 4 interleaved chain walks; support row = 128 B bf16.
// ---------------------------------------------------------------------------
__global__ __launch_bounds__(256)
void k_gather(const unsigned short* __restrict__ sup,
              const int* __restrict__ head, const int2* __restrict__ rec,
              const float* __restrict__ bias, float* __restrict__ out,
              int n_nodes) {
    int wid  = (blockIdx.x * 256 + threadIdx.x) >> 6;   // node id
    int lane = threadIdx.x & 63;                        // feature id
    if (wid >= n_nodes) return;

    int e0 = head[NCHAIN * wid + 0];
    int e1 = head[NCHAIN * wid + 1];
    int e2 = head[NCHAIN * wid + 2];
    int e3 = head[NCHAIN * wid + 3];

    float a0 = 0.f, a1 = 0.f, a2 = 0.f, a3 = 0.f;

    // AND is negative iff ALL chain ids are -1 (done)
    while ((e0 & e1 & e2 & e3) >= 0) {
        if (e0 >= 0) {
            int2 r = rec[e0];
            float s = __uint_as_float(
                (unsigned int)sup[(size_t)(r.y & 0xFFFF) * DOUT + lane] << 16);
            a0 += s * __uint_as_float((unsigned int)r.y & 0xFFFF0000u);
            e0 = r.x;
        }
        if (e1 >= 0) {
            int2 r = rec[e1];
            float s = __uint_as_float(
                (unsigned int)sup[(size_t)(r.y & 0xFFFF) * DOUT + lane] << 16);
            a1 += s * __uint_as_float((unsigned int)r.y & 0xFFFF0000u);
            e1 = r.x;
        }
        if (e2 >= 0) {
            int2 r = rec[e2];
            float s = __uint_as_float(
                (unsigned int)sup[(size_t)(r.y & 0xFFFF) * DOUT + lane] << 16);
            a2 += s * __uint_as_float((unsigned int)r.y & 0xFFFF0000u);
            e2 = r.x;
        }
        if (e3 >= 0) {
            int2 r = rec[e3];
            float s = __uint_as_float(
                (unsigned int)sup[(size_t)(r.y & 0xFFFF) * DOUT + lane] << 16);
            a3 += s * __uint_as_float((unsigned int)r.y & 0xFFFF0000u);
            e3 = r.x;
        }
    }

    float v = ((a0 + a1) + (a2 + a3)) + bias[lane];
    out[(size_t)wid * DOUT + lane] = v > 0.f ? v : expm1f(v);
}

// ---------------------------------------------------------------------------
extern "C" void kernel_launch(void* const* d_in, const int* in_sizes, int n_in,
                              void* d_out, int out_size, void* d_ws, size_t ws_size,
                              hipStream_t stream) {
    const float* x     = (const float*)d_in[0];
    const int*   esrc  = (const int*)  d_in[1];
    const int*   edst  = (const int*)  d_in[2];
    const float* evals = (const float*)d_in[3];
    const float* w     = (const float*)d_in[4];
    const float* bias  = (const float*)d_in[5];
    float* out = (float*)d_out;

    const int n_nodes = in_sizes[0] / DIN;
    const int n_edges = in_sizes[1];

    // workspace layout (256B aligned slices)
    char* p = (char*)d_ws;
    auto alloc = [&](size_t bytes) {
        char* r = p;
        p += (bytes + 255) & ~(size_t)255;
        return r;
    };
    unsigned short* sup = (unsigned short*)alloc((size_t)n_nodes * DOUT * 2); // 6.4 MB
    int*  head = (int*) alloc((size_t)n_nodes * NCHAIN * sizeof(int));        // 0.8 MB
    int2* rec  = (int2*)alloc((size_t)n_edges * sizeof(int2));                // 6.4 MB

    // head = -1 everywhere
    hipMemsetAsync(head, 0xFF, (size_t)n_nodes * NCHAIN * sizeof(int), stream);

    // 1) support = bf16(X @ W)
    gcn_gemm<<<(n_nodes + 31) / 32, 256, 0, stream>>>(x, w, sup, n_nodes);

    // 2) linked-list build
    k_build<<<(n_edges + 255) / 256, 256, 0, stream>>>(esrc, edst, evals,
                                                       head, rec, n_edges);

    // 3) gather-reduce + bias + ELU
    int blocks = (n_nodes * 64 + 255) / 256;
    k_gather<<<blocks, 256, 0, stream>>>(sup, head, rec, bias, out, n_nodes);
}

// Round 6
// 184.397 us; speedup vs baseline: 3.5441x; 3.5441x over previous
//
#include <hip/hip_runtime.h>
#include <hip/hip_bf16.h>
#include <math.h>

#define DIN 128
#define DOUT 64
#define NCHAIN 4   // parallel chains per node (ILP on the pointer chase)

__device__ __forceinline__ unsigned short f2bf(float f) {
    __hip_bfloat16 h = __float2bfloat16(f);   // round-to-nearest-even
    return *reinterpret_cast<unsigned short*>(&h);
}

// ---------------------------------------------------------------------------
// Kernel 1: support = bf16(X @ W)   [n x 128] @ [128 x 64] -> [n x 64] bf16
// Round-3 geometry (never the bottleneck): 16 rows/block, 1 row/thread,
// single float4 accumulator. 2-rows/thread variant spilled (VGPR=256,
// FETCH 604 MB of scratch traffic) -- do not widen.
// ---------------------------------------------------------------------------
__global__ __launch_bounds__(256)
void gcn_gemm(const float* __restrict__ x, const float* __restrict__ w,
              unsigned short* __restrict__ sup, int n_nodes) {
    __shared__ float ws[DIN][DOUT];      // 32 KB
    __shared__ float xs[16][DIN + 4];    // 8.4 KB

    const int t = threadIdx.x;
    const int base = blockIdx.x * 16;

    for (int i = t; i < (DIN * DOUT) / 4; i += 256)
        reinterpret_cast<float4*>(&ws[0][0])[i] =
            reinterpret_cast<const float4*>(w)[i];

    for (int i = t; i < 16 * (DIN / 4); i += 256) {
        int row = i >> 5, kq = i & 31;
        if (base + row < n_nodes) {
            float4 v = reinterpret_cast<const float4*>(x)[
                (size_t)(base + row) * (DIN / 4) + kq];
            *reinterpret_cast<float4*>(&xs[row][kq * 4]) = v;
        }
    }
    __syncthreads();

    const int r = t >> 4;
    const int c = t & 15;

    float4 acc = {0.f, 0.f, 0.f, 0.f};
    #pragma unroll
    for (int k0 = 0; k0 < DIN; k0 += 4) {
        float4 xv = *reinterpret_cast<const float4*>(&xs[r][k0]);
        float4 w0 = *reinterpret_cast<const float4*>(&ws[k0 + 0][c * 4]);
        float4 w1 = *reinterpret_cast<const float4*>(&ws[k0 + 1][c * 4]);
        float4 w2 = *reinterpret_cast<const float4*>(&ws[k0 + 2][c * 4]);
        float4 w3 = *reinterpret_cast<const float4*>(&ws[k0 + 3][c * 4]);
        acc.x += xv.x * w0.x + xv.y * w1.x + xv.z * w2.x + xv.w * w3.x;
        acc.y += xv.x * w0.y + xv.y * w1.y + xv.z * w2.y + xv.w * w3.y;
        acc.z += xv.x * w0.z + xv.y * w1.z + xv.z * w2.z + xv.w * w3.z;
        acc.w += xv.x * w0.w + xv.y * w1.w + xv.z * w2.w + xv.w * w3.w;
    }

    int row = base + r;
    if (row < n_nodes) {
        ushort4 o = { f2bf(acc.x), f2bf(acc.y), f2bf(acc.z), f2bf(acc.w) };
        reinterpret_cast<ushort4*>(sup)[(size_t)row * (DOUT / 4) + c] = o;
    }
}

// ---------------------------------------------------------------------------
// Kernel 2: build per-destination linked lists (NCHAIN chains per node).
// rec packs {next:i32, src:u16 | val:bf16<<16} in 8 B (n_nodes < 65536).
// ---------------------------------------------------------------------------
__global__ __launch_bounds__(256)
void k_build(const int* __restrict__ esrc, const int* __restrict__ edst,
             const float* __restrict__ evals, int* __restrict__ head,
             int2* __restrict__ rec, int n_edges) {
    int i = blockIdx.x * 256 + threadIdx.x;
    if (i >= n_edges) return;
    int d = edst[i];
    int prev = atomicExch(&head[NCHAIN * d + (i & (NCHAIN - 1))], i);
    unsigned int packed = (unsigned int)(esrc[i] & 0xFFFF) |
                          ((unsigned int)f2bf(evals[i]) << 16);
    rec[i] = make_int2(prev, (int)packed);
}

// ---------------------------------------------------------------------------
// Kernel 3: per-node gather-reduce + bias + ELU. One wave per node,
// lane = feature. 4 interleaved chain walks; support row = 128 B bf16.
// ---------------------------------------------------------------------------
__global__ __launch_bounds__(256)
void k_gather(const unsigned short* __restrict__ sup,
              const int* __restrict__ head, const int2* __restrict__ rec,
              const float* __restrict__ bias, float* __restrict__ out,
              int n_nodes) {
    int wid  = (blockIdx.x * 256 + threadIdx.x) >> 6;   // node id
    int lane = threadIdx.x & 63;                        // feature id
    if (wid >= n_nodes) return;

    int e0 = head[NCHAIN * wid + 0];
    int e1 = head[NCHAIN * wid + 1];
    int e2 = head[NCHAIN * wid + 2];
    int e3 = head[NCHAIN * wid + 3];

    float a0 = 0.f, a1 = 0.f, a2 = 0.f, a3 = 0.f;

    // AND is negative iff ALL chain ids are -1 (done)
    while ((e0 & e1 & e2 & e3) >= 0) {
        if (e0 >= 0) {
            int2 r = rec[e0];
            float s = __uint_as_float(
                (unsigned int)sup[(size_t)(r.y & 0xFFFF) * DOUT + lane] << 16);
            a0 += s * __uint_as_float((unsigned int)r.y & 0xFFFF0000u);
            e0 = r.x;
        }
        if (e1 >= 0) {
            int2 r = rec[e1];
            float s = __uint_as_float(
                (unsigned int)sup[(size_t)(r.y & 0xFFFF) * DOUT + lane] << 16);
            a1 += s * __uint_as_float((unsigned int)r.y & 0xFFFF0000u);
            e1 = r.x;
        }
        if (e2 >= 0) {
            int2 r = rec[e2];
            float s = __uint_as_float(
                (unsigned int)sup[(size_t)(r.y & 0xFFFF) * DOUT + lane] << 16);
            a2 += s * __uint_as_float((unsigned int)r.y & 0xFFFF0000u);
            e2 = r.x;
        }
        if (e3 >= 0) {
            int2 r = rec[e3];
            float s = __uint_as_float(
                (unsigned int)sup[(size_t)(r.y & 0xFFFF) * DOUT + lane] << 16);
            a3 += s * __uint_as_float((unsigned int)r.y & 0xFFFF0000u);
            e3 = r.x;
        }
    }

    float v = ((a0 + a1) + (a2 + a3)) + bias[lane];
    out[(size_t)wid * DOUT + lane] = v > 0.f ? v : expm1f(v);
}

// ---------------------------------------------------------------------------
extern "C" void kernel_launch(void* const* d_in, const int* in_sizes, int n_in,
                              void* d_out, int out_size, void* d_ws, size_t ws_size,
                              hipStream_t stream) {
    const float* x     = (const float*)d_in[0];
    const int*   esrc  = (const int*)  d_in[1];
    const int*   edst  = (const int*)  d_in[2];
    const float* evals = (const float*)d_in[3];
    const float* w     = (const float*)d_in[4];
    const float* bias  = (const float*)d_in[5];
    float* out = (float*)d_out;

    const int n_nodes = in_sizes[0] / DIN;
    const int n_edges = in_sizes[1];

    // workspace layout (256B aligned slices)
    char* p = (char*)d_ws;
    auto alloc = [&](size_t bytes) {
        char* r = p;
        p += (bytes + 255) & ~(size_t)255;
        return r;
    };
    unsigned short* sup = (unsigned short*)alloc((size_t)n_nodes * DOUT * 2); // 6.4 MB
    int*  head = (int*) alloc((size_t)n_nodes * NCHAIN * sizeof(int));        // 0.8 MB
    int2* rec  = (int2*)alloc((size_t)n_edges * sizeof(int2));                // 6.4 MB

    // head = -1 everywhere
    hipMemsetAsync(head, 0xFF, (size_t)n_nodes * NCHAIN * sizeof(int), stream);

    // 1) support = bf16(X @ W)
    gcn_gemm<<<(n_nodes + 15) / 16, 256, 0, stream>>>(x, w, sup, n_nodes);

    // 2) linked-list build
    k_build<<<(n_edges + 255) / 256, 256, 0, stream>>>(esrc, edst, evals,
                                                       head, rec, n_edges);

    // 3) gather-reduce + bias + ELU
    int blocks = (n_nodes * 64 + 255) / 256;
    k_gather<<<blocks, 256, 0, stream>>>(sup, head, rec, bias, out, n_nodes);
}